// Round 14
// baseline (57.003 us; speedup 1.0000x reference)
//
#include <hip/hip_runtime.h>

// SGC: out = A^K (x w) + b, A = D^-1/2 (Adj+I) D^-1/2, K=2, on per-node scalars y = x.w.
// Evidence log:
//  R1/R2: per-edge device-scope atomics ~16.7 G/s -> 48us/pass. Dead.
//  R6 coop grid.sync 285us; R10 agent-scope tickets 75us. Dead.
//  R9 REP diag: warm work ~28us; each kernel pays ~3-4us cold (cross-XCD L3 re-pull).
//  R12 lesson: fused hops need R7-grade TLP + per-record cost (no binary search).
//  R13 = 51.7us (best): 4 dispatches, ka2 bin+dot, kh3 hop+epilogue 196x512.
//  R14: kh4 = 4 runs in flight per wave (4x MLP on the rec->gather->ds_add chain);
//       dot = float4, 2 nodes/wave (16B/lane, guide G13).

#define CH2_LG   8
#define CH2      256
#define TILEB    8192
#define CAP2     96         // slots per (chunk,tile) run; lambda=41.8, +8.3 sigma
#define MAXC2    256
#define MAXNT    128

// ---------- K1: blocks [0,nbin) bin one tile via LDS counting sort; rest: y = x.w ----------
__global__ __launch_bounds__(256)
void ka2(const float* __restrict__ x, const int* __restrict__ src,
         const int* __restrict__ dst, const float* __restrict__ W,
         int n, int E, int nbin, int NT, int C,
         unsigned* __restrict__ binned, int* __restrict__ bcnt, float* __restrict__ y)
{
    const int t = threadIdx.x, bid = blockIdx.x;
    if (bid < nbin) {
        __shared__ unsigned recs[TILEB];                  // 32 KB
        __shared__ int hist[MAXC2], sc[MAXC2], cur[MAXC2];
        hist[t] = 0;
        __syncthreads();
        const int e0 = bid * TILEB;
        const int nrec = min(E - e0, TILEB);
        unsigned rl[TILEB / 256]; int chl[TILEB / 256];
        #pragma unroll
        for (int k = 0; k < TILEB / 256; k++) {
            int j = k * 256 + t;
            if (j < nrec) {
                int s = src[e0 + j], d = dst[e0 + j];
                chl[k] = d >> CH2_LG;
                rl[k]  = ((unsigned)chl[k] << 24) | ((unsigned)(d & (CH2 - 1)) << 16) | (unsigned)s;
                atomicAdd(&hist[chl[k]], 1);
            } else chl[k] = -1;
        }
        __syncthreads();
        sc[t] = hist[t];
        __syncthreads();
        #pragma unroll
        for (int off = 1; off < MAXC2; off <<= 1) {       // Hillis-Steele inclusive scan
            int v = (t >= off) ? sc[t - off] : 0;
            __syncthreads();
            sc[t] += v;
            __syncthreads();
        }
        cur[t] = sc[t] - hist[t];                         // exclusive base
        if (t < C) bcnt[t * NT + bid] = min(hist[t], CAP2);
        __syncthreads();
        #pragma unroll
        for (int k = 0; k < TILEB / 256; k++)             // scatter into LDS, bucket-sorted
            if (chl[k] >= 0) recs[atomicAdd(&cur[chl[k]], 1)] = rl[k];
        __syncthreads();
        for (int j = t; j < nrec; j += 256) {             // coalesced run write-out
            unsigned r = recs[j];
            int ch  = r >> 24;
            int off = j - (sc[ch] - hist[ch]);
            if (off < CAP2)
                binned[((size_t)ch * NT + bid) * CAP2 + off] = r & 0x00FFFFFFu;
        }
    } else {
        // dot: 2 nodes per wave, float4 (16B/lane)
        const int lane = t & 63;
        const int half = lane >> 5, l32 = lane & 31;
        const float4 wv = ((const float4*)W)[l32];
        int i = (bid - nbin) * 8 + (t >> 6) * 2 + half;
        if (i < n) {
            float4 xv = ((const float4*)(x + (size_t)i * 128))[l32];
            float v = xv.x * wv.x + xv.y * wv.y + xv.z * wv.z + xv.w * wv.w;
            #pragma unroll
            for (int off = 16; off; off >>= 1) v += __shfl_xor(v, off);
            if (l32 == 0) y[i] = v;
        }
    }
}

// ---------- hop + fused epilogue: block c owns chunk c (256 nodes), 8 waves, 4-way MLP ----------
// V0: deg -> dis=rsqrt(deg+1), u=dis*y   V1: u2=dis^2*(s+u)   V2: out=dis*(s+u2)+b
template <int V>
__global__ __launch_bounds__(512)
void kh4(const unsigned* __restrict__ binned, const int* __restrict__ bcnt,
         int NT, int n, const float* __restrict__ y, float* __restrict__ dis,
         float* __restrict__ u, float* __restrict__ u2,
         const float* __restrict__ bias, float* __restrict__ out)
{
    __shared__ float acc[CH2];
    __shared__ int lens[MAXNT];
    const int c = blockIdx.x, t = threadIdx.x;
    if (t < CH2) acc[t] = 0.f;
    if (t < MAXNT) lens[t] = (t < NT) ? bcnt[c * NT + t] : 0;   // one coalesced lens read
    __syncthreads();
    const int w = t >> 6, ln = t & 63;
    const unsigned* bb = binned + (size_t)c * NT * CAP2;
    const float* val = (V == 1) ? u : u2;
    for (int b0 = w; b0 < NT; b0 += 32) {                 // 4 runs in flight: b0,+8,+16,+24
        int  bi[4], len[4]; unsigned r[4]; bool ok[4];
        #pragma unroll
        for (int q = 0; q < 4; q++) {
            bi[q]  = b0 + 8 * q;
            len[q] = (bi[q] < NT) ? lens[bi[q]] : 0;
            ok[q]  = ln < len[q];
            if (ok[q]) r[q] = bb[(size_t)bi[q] * CAP2 + ln];
        }
        float v[4];
        #pragma unroll
        for (int q = 0; q < 4; q++)
            if (ok[q]) v[q] = (V == 0) ? 1.0f : val[r[q] & 0xFFFFu];
        #pragma unroll
        for (int q = 0; q < 4; q++)
            if (ok[q]) atomicAdd(&acc[(r[q] >> 16) & 0xFFu], v[q]);   // ds_add_f32
        #pragma unroll
        for (int q = 0; q < 4; q++) {                     // rare tail: len > 64
            for (int j = 64 + ln; j < len[q]; j += 64) {
                unsigned rr = bb[(size_t)bi[q] * CAP2 + j];
                float vv = (V == 0) ? 1.0f : val[rr & 0xFFFFu];
                atomicAdd(&acc[(rr >> 16) & 0xFFu], vv);
            }
        }
    }
    __syncthreads();
    if (t < CH2) {
        const int i = (c << CH2_LG) + t;                  // thread t <-> node
        if (i < n) {
            float a = acc[t];
            if (V == 0) { float d = rsqrtf(a + 1.0f); dis[i] = d; u[i] = d * y[i]; }
            if (V == 1) { float d = dis[i]; u2[i] = d * d * (a + u[i]); }
            if (V == 2) { out[i] = dis[i] * (a + u2[i]) + bias[0]; }
        }
    }
}

// ---------------- fallback (R5 proven path, ~63 us) ----------------
#define CHUNK_LG  10
#define CHUNK     1024
#define NCHMAX    64
#define NSLAB     16
#define RECS      7

__global__ void k_zero(int* __restrict__ cnt) { cnt[threadIdx.x] = 0; }

__global__ void k_bin(const int* __restrict__ src, const int* __restrict__ dst,
                      int E, int nchunks, int cap,
                      int* __restrict__ cnt, unsigned int* __restrict__ binned) {
    __shared__ int hist[NCHMAX], base[NCHMAX], cur[NCHMAX];
    int t = threadIdx.x;
    if (t < NCHMAX) { hist[t] = 0; cur[t] = 0; }
    __syncthreads();
    int e0 = blockIdx.x * (RECS * 256);
    unsigned int rec[RECS]; int ch[RECS];
    #pragma unroll
    for (int k = 0; k < RECS; k++) {
        int e = e0 + k * 256 + t;
        if (e < E) {
            int s = src[e], d = dst[e];
            ch[k]  = d >> CHUNK_LG;
            rec[k] = ((unsigned)(d & (CHUNK - 1)) << 16) | (unsigned)s;
            atomicAdd(&hist[ch[k]], 1);
        } else ch[k] = -1;
    }
    __syncthreads();
    if (t < nchunks) base[t] = atomicAdd(&cnt[t], hist[t]);
    __syncthreads();
    #pragma unroll
    for (int k = 0; k < RECS; k++) {
        if (ch[k] >= 0) {
            int slot = base[ch[k]] + atomicAdd(&cur[ch[k]], 1);
            if (slot < cap) binned[(size_t)ch[k] * cap + slot] = rec[k];
        }
    }
}

template <int MODE>
__global__ void k_hop(const unsigned int* __restrict__ binned, const int* __restrict__ cnt,
                      int cap, const float* __restrict__ val, float* __restrict__ partial) {
    __shared__ float acc[CHUNK];
    int c = blockIdx.x >> 4;
    int m = blockIdx.x & (NSLAB - 1);
    int t = threadIdx.x;
    #pragma unroll
    for (int k = 0; k < CHUNK / 256; k++) acc[t + k * 256] = 0.f;
    __syncthreads();
    int nc = cnt[c]; if (nc > cap) nc = cap;
    const unsigned int* bb = binned + (size_t)c * cap;
    for (int e = m * 256 + t; e < nc; e += NSLAB * 256) {
        unsigned int r = bb[e];
        float v = (MODE == 0) ? 1.0f : val[r & 0xFFFFu];
        atomicAdd(&acc[r >> 16], v);
    }
    __syncthreads();
    float* pp = partial + ((size_t)(c * NSLAB + m) << CHUNK_LG);
    #pragma unroll
    for (int k = 0; k < CHUNK / 256; k++) pp[t + k * 256] = acc[t + k * 256];
}

__global__ void k_dot(const float* __restrict__ x, const float* __restrict__ W,
                      float* __restrict__ y, int n) {
    int wid  = (blockIdx.x * blockDim.x + threadIdx.x) >> 6;
    int lane = threadIdx.x & 63;
    if (wid >= n) return;
    float2 xv = ((const float2*)(x + (size_t)wid * 128))[lane];
    float2 wv = ((const float2*)W)[lane];
    float v = xv.x * wv.x + xv.y * wv.y;
    #pragma unroll
    for (int off = 32; off; off >>= 1) v += __shfl_xor(v, off);
    if (lane == 0) y[wid] = v;
}

template <int V>
__global__ void k_reduce(const float* __restrict__ partial, int n,
                         const float* __restrict__ y, float* __restrict__ dis,
                         float* __restrict__ u, float* __restrict__ u2,
                         const float* __restrict__ b, float* __restrict__ out) {
    int i = blockIdx.x * blockDim.x + threadIdx.x;
    if (i >= n) return;
    int c = i >> CHUNK_LG, l = i & (CHUNK - 1);
    const float* pp = partial + ((size_t)(c * NSLAB) << CHUNK_LG) + l;
    float s = 0.f;
    #pragma unroll
    for (int m = 0; m < NSLAB; m++) s += pp[m << CHUNK_LG];
    if (V == 0) { float d = rsqrtf(s + 1.0f); dis[i] = d; u[i] = d * y[i]; }
    if (V == 1) { float d = dis[i]; u2[i] = d * d * (s + u[i]); }
    if (V == 2) { out[i] = dis[i] * (s + u2[i]) + b[0]; }
}

extern "C" void kernel_launch(void* const* d_in, const int* in_sizes, int n_in,
                              void* d_out, int out_size, void* d_ws, size_t ws_size,
                              hipStream_t stream) {
    const float* x  = (const float*)d_in[0];
    const int*   ei = (const int*)d_in[1];   // [2,E]; row0=src, row1=dst
    const float* W  = (const float*)d_in[2];
    const float* b  = (const float*)d_in[3];
    float* out = (float*)d_out;

    const int n = out_size;            // 50000
    const int E = in_sizes[1] / 2;     // 800000
    const int D = in_sizes[0] / n;     // 128
    const int* src = ei;
    const int* dst = ei + E;

    const int C2  = (n + CH2 - 1) >> CH2_LG;               // 196
    const int NT2 = (E + TILEB - 1) / TILEB;               // 98

    // fast-path ws (words): binned[C2*NT2*CAP2] | bcnt[C2*NT2] | y | dis | u | u2
    size_t w_binned = (size_t)C2 * NT2 * CAP2;
    size_t w_bcnt   = (size_t)C2 * NT2;
    size_t need     = (w_binned + w_bcnt + 4 * (size_t)n) * 4;

    if (D == 128 && n <= 65536 && C2 <= MAXC2 && NT2 <= MAXNT && ws_size >= need) {
        unsigned* binned = (unsigned*)d_ws;
        int*      bcnt   = (int*)d_ws + w_binned;
        float*    y      = (float*)d_ws + w_binned + w_bcnt;
        float*    dis    = y + n;
        float*    u      = dis + n;
        float*    u2     = u + n;

        const int gridA = NT2 + (n + 7) / 8;               // bin blocks + dot blocks (8 nodes/blk)

        ka2<<<gridA, 256, 0, stream>>>(x, src, dst, W, n, E, NT2, NT2, C2, binned, bcnt, y);
        kh4<0><<<C2, 512, 0, stream>>>(binned, bcnt, NT2, n, y, dis, u, u2, b, out);  // deg->dis,u
        kh4<1><<<C2, 512, 0, stream>>>(binned, bcnt, NT2, n, y, dis, u, u2, b, out);  // hop1->u2
        kh4<2><<<C2, 512, 0, stream>>>(binned, bcnt, NT2, n, y, dis, u, u2, b, out);  // hop2->out
        return;
    }

    // fallback: R5 proven binned multi-kernel path (CHUNK=1024)
    {
        const int TBf = 256;
        const int Cf  = (n + CHUNK - 1) >> CHUNK_LG;
        const int cap = (int)((long long)E * 5 / (4 * Cf)) + 512;
        int*          cnt    = (int*)d_ws;
        unsigned int* binned = (unsigned int*)(cnt + 64);
        float*        part   = (float*)(binned + (size_t)Cf * cap);
        float*        y      = part + (size_t)Cf * NSLAB * CHUNK;
        float*        dis    = y + n;
        float*        u      = dis + n;
        float*        u2     = u + n;

        const int binBlocks = (E + RECS * 256 - 1) / (RECS * 256);
        const int hopBlocks = Cf * NSLAB;
        const int nb        = (n + TBf - 1) / TBf;
        const int dotBlocks = ((size_t)n * 64 + TBf - 1) / TBf;

        k_zero<<<1, 64, 0, stream>>>(cnt);
        k_bin<<<binBlocks, TBf, 0, stream>>>(src, dst, E, Cf, cap, cnt, binned);
        k_dot<<<dotBlocks, TBf, 0, stream>>>(x, W, y, n);
        k_hop<0><<<hopBlocks, TBf, 0, stream>>>(binned, cnt, cap, y, part);
        k_reduce<0><<<nb, TBf, 0, stream>>>(part, n, y, dis, u, u2, b, out);
        k_hop<1><<<hopBlocks, TBf, 0, stream>>>(binned, cnt, cap, u, part);
        k_reduce<1><<<nb, TBf, 0, stream>>>(part, n, y, dis, u, u2, b, out);
        k_hop<1><<<hopBlocks, TBf, 0, stream>>>(binned, cnt, cap, u2, part);
        k_reduce<2><<<nb, TBf, 0, stream>>>(part, n, y, dis, u, u2, b, out);
    }
}

// Round 15
// 51.992 us; speedup vs baseline: 1.0964x; 1.0964x over previous
//
#include <hip/hip_runtime.h>

// SGC: out = A^K (x w) + b, A = D^-1/2 (Adj+I) D^-1/2, K=2, on per-node scalars y = x.w.
// Evidence log:
//  R1/R2: per-edge device-scope atomics ~16.7 G/s -> 48us/pass. Dead.
//  R6 coop grid.sync 285us; R10 agent-scope tickets 75us. Dead.
//  R9 REP diag: warm work ~28us; each kernel pays ~3-4us cold (cross-XCD L3 re-pull).
//  R12 lesson: fused hops need R7-grade TLP + per-record cost (no binary search).
//  R13 = 51.7us (BEST): 4 dispatches, ka2 bin+dot, kh3 hop+epilogue 196 x 512thr.
//  R14 = 57.0us: explicit 4-run MLP in hop REGRESSED (compiler already pipelines the
//    simple loop; extra regs + predication hurt) — Common-mistake #5 confirmed.
//  R15: kh3 reverted to R13 verbatim; keep ONLY the float4 dot (G13, isolated).

#define CH2_LG   8
#define CH2      256
#define TILEB    8192
#define CAP2     96         // slots per (chunk,tile) run; lambda=41.8, +8.3 sigma
#define MAXC2    256
#define MAXNT    128

// ---------- K1: blocks [0,nbin) bin one tile via LDS counting sort; rest: y = x.w ----------
__global__ __launch_bounds__(256)
void ka2(const float* __restrict__ x, const int* __restrict__ src,
         const int* __restrict__ dst, const float* __restrict__ W,
         int n, int E, int nbin, int NT, int C,
         unsigned* __restrict__ binned, int* __restrict__ bcnt, float* __restrict__ y)
{
    const int t = threadIdx.x, bid = blockIdx.x;
    if (bid < nbin) {
        __shared__ unsigned recs[TILEB];                  // 32 KB
        __shared__ int hist[MAXC2], sc[MAXC2], cur[MAXC2];
        hist[t] = 0;
        __syncthreads();
        const int e0 = bid * TILEB;
        const int nrec = min(E - e0, TILEB);
        unsigned rl[TILEB / 256]; int chl[TILEB / 256];
        #pragma unroll
        for (int k = 0; k < TILEB / 256; k++) {
            int j = k * 256 + t;
            if (j < nrec) {
                int s = src[e0 + j], d = dst[e0 + j];
                chl[k] = d >> CH2_LG;
                rl[k]  = ((unsigned)chl[k] << 24) | ((unsigned)(d & (CH2 - 1)) << 16) | (unsigned)s;
                atomicAdd(&hist[chl[k]], 1);
            } else chl[k] = -1;
        }
        __syncthreads();
        sc[t] = hist[t];
        __syncthreads();
        #pragma unroll
        for (int off = 1; off < MAXC2; off <<= 1) {       // Hillis-Steele inclusive scan
            int v = (t >= off) ? sc[t - off] : 0;
            __syncthreads();
            sc[t] += v;
            __syncthreads();
        }
        cur[t] = sc[t] - hist[t];                         // exclusive base
        if (t < C) bcnt[t * NT + bid] = min(hist[t], CAP2);
        __syncthreads();
        #pragma unroll
        for (int k = 0; k < TILEB / 256; k++)             // scatter into LDS, bucket-sorted
            if (chl[k] >= 0) recs[atomicAdd(&cur[chl[k]], 1)] = rl[k];
        __syncthreads();
        for (int j = t; j < nrec; j += 256) {             // coalesced run write-out
            unsigned r = recs[j];
            int ch  = r >> 24;
            int off = j - (sc[ch] - hist[ch]);
            if (off < CAP2)
                binned[((size_t)ch * NT + bid) * CAP2 + off] = r & 0x00FFFFFFu;
        }
    } else {
        // dot: 2 nodes per wave, float4 (16B/lane, G13)
        const int lane = t & 63;
        const int half = lane >> 5, l32 = lane & 31;
        const float4 wv = ((const float4*)W)[l32];
        int i = (bid - nbin) * 8 + (t >> 6) * 2 + half;
        if (i < n) {
            float4 xv = ((const float4*)(x + (size_t)i * 128))[l32];
            float v = xv.x * wv.x + xv.y * wv.y + xv.z * wv.z + xv.w * wv.w;
            #pragma unroll
            for (int off = 16; off; off >>= 1) v += __shfl_xor(v, off);
            if (l32 == 0) y[i] = v;
        }
    }
}

// ---------- hop + fused epilogue: block c owns chunk c (256 nodes), 8 waves (R13 verbatim) ----------
// V0: deg -> dis=rsqrt(deg+1), u=dis*y   V1: u2=dis^2*(s+u)   V2: out=dis*(s+u2)+b
template <int V>
__global__ __launch_bounds__(512)
void kh3(const unsigned* __restrict__ binned, const int* __restrict__ bcnt,
         int NT, int n, const float* __restrict__ y, float* __restrict__ dis,
         float* __restrict__ u, float* __restrict__ u2,
         const float* __restrict__ bias, float* __restrict__ out)
{
    __shared__ float acc[CH2];
    __shared__ int lens[MAXNT];
    const int c = blockIdx.x, t = threadIdx.x;
    if (t < CH2) acc[t] = 0.f;
    if (t < MAXNT) lens[t] = (t < NT) ? bcnt[c * NT + t] : 0;   // one coalesced lens read
    __syncthreads();
    const int w = t >> 6, ln = t & 63;
    const unsigned* bb = binned + (size_t)c * NT * CAP2;
    for (int b = w; b < NT; b += 8) {                     // wave w owns runs w, w+8, ...
        int len = lens[b];                                // LDS broadcast, 1 per run
        const unsigned* run = bb + (size_t)b * CAP2;
        for (int j = ln; j < len; j += 64) {
            unsigned r = run[j];
            float v = (V == 0) ? 1.0f : ((V == 1) ? u[r & 0xFFFFu] : u2[r & 0xFFFFu]);
            atomicAdd(&acc[(r >> 16) & 0xFFu], v);        // ds_add_f32
        }
    }
    __syncthreads();
    if (t < CH2) {
        const int i = (c << CH2_LG) + t;                  // thread t <-> node
        if (i < n) {
            float a = acc[t];
            if (V == 0) { float d = rsqrtf(a + 1.0f); dis[i] = d; u[i] = d * y[i]; }
            if (V == 1) { float d = dis[i]; u2[i] = d * d * (a + u[i]); }
            if (V == 2) { out[i] = dis[i] * (a + u2[i]) + bias[0]; }
        }
    }
}

// ---------------- fallback (R5 proven path, ~63 us) ----------------
#define CHUNK_LG  10
#define CHUNK     1024
#define NCHMAX    64
#define NSLAB     16
#define RECS      7

__global__ void k_zero(int* __restrict__ cnt) { cnt[threadIdx.x] = 0; }

__global__ void k_bin(const int* __restrict__ src, const int* __restrict__ dst,
                      int E, int nchunks, int cap,
                      int* __restrict__ cnt, unsigned int* __restrict__ binned) {
    __shared__ int hist[NCHMAX], base[NCHMAX], cur[NCHMAX];
    int t = threadIdx.x;
    if (t < NCHMAX) { hist[t] = 0; cur[t] = 0; }
    __syncthreads();
    int e0 = blockIdx.x * (RECS * 256);
    unsigned int rec[RECS]; int ch[RECS];
    #pragma unroll
    for (int k = 0; k < RECS; k++) {
        int e = e0 + k * 256 + t;
        if (e < E) {
            int s = src[e], d = dst[e];
            ch[k]  = d >> CHUNK_LG;
            rec[k] = ((unsigned)(d & (CHUNK - 1)) << 16) | (unsigned)s;
            atomicAdd(&hist[ch[k]], 1);
        } else ch[k] = -1;
    }
    __syncthreads();
    if (t < nchunks) base[t] = atomicAdd(&cnt[t], hist[t]);
    __syncthreads();
    #pragma unroll
    for (int k = 0; k < RECS; k++) {
        if (ch[k] >= 0) {
            int slot = base[ch[k]] + atomicAdd(&cur[ch[k]], 1);
            if (slot < cap) binned[(size_t)ch[k] * cap + slot] = rec[k];
        }
    }
}

template <int MODE>
__global__ void k_hop(const unsigned int* __restrict__ binned, const int* __restrict__ cnt,
                      int cap, const float* __restrict__ val, float* __restrict__ partial) {
    __shared__ float acc[CHUNK];
    int c = blockIdx.x >> 4;
    int m = blockIdx.x & (NSLAB - 1);
    int t = threadIdx.x;
    #pragma unroll
    for (int k = 0; k < CHUNK / 256; k++) acc[t + k * 256] = 0.f;
    __syncthreads();
    int nc = cnt[c]; if (nc > cap) nc = cap;
    const unsigned int* bb = binned + (size_t)c * cap;
    for (int e = m * 256 + t; e < nc; e += NSLAB * 256) {
        unsigned int r = bb[e];
        float v = (MODE == 0) ? 1.0f : val[r & 0xFFFFu];
        atomicAdd(&acc[r >> 16], v);
    }
    __syncthreads();
    float* pp = partial + ((size_t)(c * NSLAB + m) << CHUNK_LG);
    #pragma unroll
    for (int k = 0; k < CHUNK / 256; k++) pp[t + k * 256] = acc[t + k * 256];
}

__global__ void k_dot(const float* __restrict__ x, const float* __restrict__ W,
                      float* __restrict__ y, int n) {
    int wid  = (blockIdx.x * blockDim.x + threadIdx.x) >> 6;
    int lane = threadIdx.x & 63;
    if (wid >= n) return;
    float2 xv = ((const float2*)(x + (size_t)wid * 128))[lane];
    float2 wv = ((const float2*)W)[lane];
    float v = xv.x * wv.x + xv.y * wv.y;
    #pragma unroll
    for (int off = 32; off; off >>= 1) v += __shfl_xor(v, off);
    if (lane == 0) y[wid] = v;
}

template <int V>
__global__ void k_reduce(const float* __restrict__ partial, int n,
                         const float* __restrict__ y, float* __restrict__ dis,
                         float* __restrict__ u, float* __restrict__ u2,
                         const float* __restrict__ b, float* __restrict__ out) {
    int i = blockIdx.x * blockDim.x + threadIdx.x;
    if (i >= n) return;
    int c = i >> CHUNK_LG, l = i & (CHUNK - 1);
    const float* pp = partial + ((size_t)(c * NSLAB) << CHUNK_LG) + l;
    float s = 0.f;
    #pragma unroll
    for (int m = 0; m < NSLAB; m++) s += pp[m << CHUNK_LG];
    if (V == 0) { float d = rsqrtf(s + 1.0f); dis[i] = d; u[i] = d * y[i]; }
    if (V == 1) { float d = dis[i]; u2[i] = d * d * (s + u[i]); }
    if (V == 2) { out[i] = dis[i] * (s + u2[i]) + b[0]; }
}

extern "C" void kernel_launch(void* const* d_in, const int* in_sizes, int n_in,
                              void* d_out, int out_size, void* d_ws, size_t ws_size,
                              hipStream_t stream) {
    const float* x  = (const float*)d_in[0];
    const int*   ei = (const int*)d_in[1];   // [2,E]; row0=src, row1=dst
    const float* W  = (const float*)d_in[2];
    const float* b  = (const float*)d_in[3];
    float* out = (float*)d_out;

    const int n = out_size;            // 50000
    const int E = in_sizes[1] / 2;     // 800000
    const int D = in_sizes[0] / n;     // 128
    const int* src = ei;
    const int* dst = ei + E;

    const int C2  = (n + CH2 - 1) >> CH2_LG;               // 196
    const int NT2 = (E + TILEB - 1) / TILEB;               // 98

    // fast-path ws (words): binned[C2*NT2*CAP2] | bcnt[C2*NT2] | y | dis | u | u2
    size_t w_binned = (size_t)C2 * NT2 * CAP2;
    size_t w_bcnt   = (size_t)C2 * NT2;
    size_t need     = (w_binned + w_bcnt + 4 * (size_t)n) * 4;

    if (D == 128 && n <= 65536 && C2 <= MAXC2 && NT2 <= MAXNT && ws_size >= need) {
        unsigned* binned = (unsigned*)d_ws;
        int*      bcnt   = (int*)d_ws + w_binned;
        float*    y      = (float*)d_ws + w_binned + w_bcnt;
        float*    dis    = y + n;
        float*    u      = dis + n;
        float*    u2     = u + n;

        const int gridA = NT2 + (n + 7) / 8;               // bin blocks + dot blocks (8 nodes/blk)

        ka2<<<gridA, 256, 0, stream>>>(x, src, dst, W, n, E, NT2, NT2, C2, binned, bcnt, y);
        kh3<0><<<C2, 512, 0, stream>>>(binned, bcnt, NT2, n, y, dis, u, u2, b, out);  // deg->dis,u
        kh3<1><<<C2, 512, 0, stream>>>(binned, bcnt, NT2, n, y, dis, u, u2, b, out);  // hop1->u2
        kh3<2><<<C2, 512, 0, stream>>>(binned, bcnt, NT2, n, y, dis, u, u2, b, out);  // hop2->out
        return;
    }

    // fallback: R5 proven binned multi-kernel path (CHUNK=1024)
    {
        const int TBf = 256;
        const int Cf  = (n + CHUNK - 1) >> CHUNK_LG;
        const int cap = (int)((long long)E * 5 / (4 * Cf)) + 512;
        int*          cnt    = (int*)d_ws;
        unsigned int* binned = (unsigned int*)(cnt + 64);
        float*        part   = (float*)(binned + (size_t)Cf * cap);
        float*        y      = part + (size_t)Cf * NSLAB * CHUNK;
        float*        dis    = y + n;
        float*        u      = dis + n;
        float*        u2     = u + n;

        const int binBlocks = (E + RECS * 256 - 1) / (RECS * 256);
        const int hopBlocks = Cf * NSLAB;
        const int nb        = (n + TBf - 1) / TBf;
        const int dotBlocks = ((size_t)n * 64 + TBf - 1) / TBf;

        k_zero<<<1, 64, 0, stream>>>(cnt);
        k_bin<<<binBlocks, TBf, 0, stream>>>(src, dst, E, Cf, cap, cnt, binned);
        k_dot<<<dotBlocks, TBf, 0, stream>>>(x, W, y, n);
        k_hop<0><<<hopBlocks, TBf, 0, stream>>>(binned, cnt, cap, y, part);
        k_reduce<0><<<nb, TBf, 0, stream>>>(part, n, y, dis, u, u2, b, out);
        k_hop<1><<<hopBlocks, TBf, 0, stream>>>(binned, cnt, cap, u, part);
        k_reduce<1><<<nb, TBf, 0, stream>>>(part, n, y, dis, u, u2, b, out);
        k_hop<1><<<hopBlocks, TBf, 0, stream>>>(binned, cnt, cap, u2, part);
        k_reduce<2><<<nb, TBf, 0, stream>>>(part, n, y, dis, u, u2, b, out);
    }
}

// Round 16
// 49.541 us; speedup vs baseline: 1.1506x; 1.0495x over previous
//
#include <hip/hip_runtime.h>

// SGC: out = A^K (x w) + b, A = D^-1/2 (Adj+I) D^-1/2, K=2, on per-node scalars y = x.w.
// Evidence log:
//  R1/R2: per-edge device-scope atomics ~16.7 G/s -> 48us/pass. Dead.
//  R6 coop grid.sync 285us; R10 agent-scope tickets 75us. Dead.
//  R9 REP diag: warm work ~28us; each kernel pays ~3-4us cold (cross-XCD L3 re-pull).
//  R13 = 51.7us (BEST): 4 dispatches, ka2 bin+dot, kh3 hop+epilogue 196 x 512thr.
//  R14 = 57.0us: explicit 4-run MLP REGRESSED (Common-mistake #5). R15 = 52.0us: float4
//    dot neutral; kh4 was the whole regression.
//  R16: hop TLP fix - 196 blocks < 256 CUs means 1 block/CU = 2 waves/SIMD; runs are
//    single-iteration (len<=64) so each is a serial rec->gather->ds_add chain (~600cy x12).
//    kh3 at 1024 thr (16 waves): 6 chains/wave, 4 waves/SIMD. Loop body untouched.

#define CH2_LG   8
#define CH2      256
#define TILEB    8192
#define CAP2     96         // slots per (chunk,tile) run; lambda=41.8, +8.3 sigma
#define MAXC2    256
#define MAXNT    128

// ---------- K1: blocks [0,nbin) bin one tile via LDS counting sort; rest: y = x.w ----------
__global__ __launch_bounds__(256)
void ka2(const float* __restrict__ x, const int* __restrict__ src,
         const int* __restrict__ dst, const float* __restrict__ W,
         int n, int E, int nbin, int NT, int C,
         unsigned* __restrict__ binned, int* __restrict__ bcnt, float* __restrict__ y)
{
    const int t = threadIdx.x, bid = blockIdx.x;
    if (bid < nbin) {
        __shared__ unsigned recs[TILEB];                  // 32 KB
        __shared__ int hist[MAXC2], sc[MAXC2], cur[MAXC2];
        hist[t] = 0;
        __syncthreads();
        const int e0 = bid * TILEB;
        const int nrec = min(E - e0, TILEB);
        unsigned rl[TILEB / 256]; int chl[TILEB / 256];
        #pragma unroll
        for (int k = 0; k < TILEB / 256; k++) {
            int j = k * 256 + t;
            if (j < nrec) {
                int s = src[e0 + j], d = dst[e0 + j];
                chl[k] = d >> CH2_LG;
                rl[k]  = ((unsigned)chl[k] << 24) | ((unsigned)(d & (CH2 - 1)) << 16) | (unsigned)s;
                atomicAdd(&hist[chl[k]], 1);
            } else chl[k] = -1;
        }
        __syncthreads();
        sc[t] = hist[t];
        __syncthreads();
        #pragma unroll
        for (int off = 1; off < MAXC2; off <<= 1) {       // Hillis-Steele inclusive scan
            int v = (t >= off) ? sc[t - off] : 0;
            __syncthreads();
            sc[t] += v;
            __syncthreads();
        }
        cur[t] = sc[t] - hist[t];                         // exclusive base
        if (t < C) bcnt[t * NT + bid] = min(hist[t], CAP2);
        __syncthreads();
        #pragma unroll
        for (int k = 0; k < TILEB / 256; k++)             // scatter into LDS, bucket-sorted
            if (chl[k] >= 0) recs[atomicAdd(&cur[chl[k]], 1)] = rl[k];
        __syncthreads();
        for (int j = t; j < nrec; j += 256) {             // coalesced run write-out
            unsigned r = recs[j];
            int ch  = r >> 24;
            int off = j - (sc[ch] - hist[ch]);
            if (off < CAP2)
                binned[((size_t)ch * NT + bid) * CAP2 + off] = r & 0x00FFFFFFu;
        }
    } else {
        // dot: 2 nodes per wave, float4 (16B/lane, G13)
        const int lane = t & 63;
        const int half = lane >> 5, l32 = lane & 31;
        const float4 wv = ((const float4*)W)[l32];
        int i = (bid - nbin) * 8 + (t >> 6) * 2 + half;
        if (i < n) {
            float4 xv = ((const float4*)(x + (size_t)i * 128))[l32];
            float v = xv.x * wv.x + xv.y * wv.y + xv.z * wv.z + xv.w * wv.w;
            #pragma unroll
            for (int off = 16; off; off >>= 1) v += __shfl_xor(v, off);
            if (l32 == 0) y[i] = v;
        }
    }
}

// ---------- hop + fused epilogue: block c owns chunk c (256 nodes), 16 waves ----------
// V0: deg -> dis=rsqrt(deg+1), u=dis*y   V1: u2=dis^2*(s+u)   V2: out=dis*(s+u2)+b
template <int V>
__global__ __launch_bounds__(1024)
void kh3(const unsigned* __restrict__ binned, const int* __restrict__ bcnt,
         int NT, int n, const float* __restrict__ y, float* __restrict__ dis,
         float* __restrict__ u, float* __restrict__ u2,
         const float* __restrict__ bias, float* __restrict__ out)
{
    __shared__ float acc[CH2];
    __shared__ int lens[MAXNT];
    const int c = blockIdx.x, t = threadIdx.x;
    if (t < CH2) acc[t] = 0.f;
    if (t >= CH2 && t < CH2 + MAXNT) {                    // different waves than acc init
        int b = t - CH2;
        lens[b] = (b < NT) ? bcnt[c * NT + b] : 0;        // one coalesced lens read
    }
    __syncthreads();
    const int w = t >> 6, ln = t & 63;                    // 16 waves
    const unsigned* bb = binned + (size_t)c * NT * CAP2;
    for (int b = w; b < NT; b += 16) {                    // wave w owns runs w, w+16, ...
        int len = lens[b];                                // LDS broadcast, 1 per run
        const unsigned* run = bb + (size_t)b * CAP2;
        for (int j = ln; j < len; j += 64) {
            unsigned r = run[j];
            float v = (V == 0) ? 1.0f : ((V == 1) ? u[r & 0xFFFFu] : u2[r & 0xFFFFu]);
            atomicAdd(&acc[(r >> 16) & 0xFFu], v);        // ds_add_f32
        }
    }
    __syncthreads();
    if (t < CH2) {
        const int i = (c << CH2_LG) + t;                  // thread t <-> node
        if (i < n) {
            float a = acc[t];
            if (V == 0) { float d = rsqrtf(a + 1.0f); dis[i] = d; u[i] = d * y[i]; }
            if (V == 1) { float d = dis[i]; u2[i] = d * d * (a + u[i]); }
            if (V == 2) { out[i] = dis[i] * (a + u2[i]) + bias[0]; }
        }
    }
}

// ---------------- fallback (R5 proven path, ~63 us) ----------------
#define CHUNK_LG  10
#define CHUNK     1024
#define NCHMAX    64
#define NSLAB     16
#define RECS      7

__global__ void k_zero(int* __restrict__ cnt) { cnt[threadIdx.x] = 0; }

__global__ void k_bin(const int* __restrict__ src, const int* __restrict__ dst,
                      int E, int nchunks, int cap,
                      int* __restrict__ cnt, unsigned int* __restrict__ binned) {
    __shared__ int hist[NCHMAX], base[NCHMAX], cur[NCHMAX];
    int t = threadIdx.x;
    if (t < NCHMAX) { hist[t] = 0; cur[t] = 0; }
    __syncthreads();
    int e0 = blockIdx.x * (RECS * 256);
    unsigned int rec[RECS]; int ch[RECS];
    #pragma unroll
    for (int k = 0; k < RECS; k++) {
        int e = e0 + k * 256 + t;
        if (e < E) {
            int s = src[e], d = dst[e];
            ch[k]  = d >> CHUNK_LG;
            rec[k] = ((unsigned)(d & (CHUNK - 1)) << 16) | (unsigned)s;
            atomicAdd(&hist[ch[k]], 1);
        } else ch[k] = -1;
    }
    __syncthreads();
    if (t < nchunks) base[t] = atomicAdd(&cnt[t], hist[t]);
    __syncthreads();
    #pragma unroll
    for (int k = 0; k < RECS; k++) {
        if (ch[k] >= 0) {
            int slot = base[ch[k]] + atomicAdd(&cur[ch[k]], 1);
            if (slot < cap) binned[(size_t)ch[k] * cap + slot] = rec[k];
        }
    }
}

template <int MODE>
__global__ void k_hop(const unsigned int* __restrict__ binned, const int* __restrict__ cnt,
                      int cap, const float* __restrict__ val, float* __restrict__ partial) {
    __shared__ float acc[CHUNK];
    int c = blockIdx.x >> 4;
    int m = blockIdx.x & (NSLAB - 1);
    int t = threadIdx.x;
    #pragma unroll
    for (int k = 0; k < CHUNK / 256; k++) acc[t + k * 256] = 0.f;
    __syncthreads();
    int nc = cnt[c]; if (nc > cap) nc = cap;
    const unsigned int* bb = binned + (size_t)c * cap;
    for (int e = m * 256 + t; e < nc; e += NSLAB * 256) {
        unsigned int r = bb[e];
        float v = (MODE == 0) ? 1.0f : val[r & 0xFFFFu];
        atomicAdd(&acc[r >> 16], v);
    }
    __syncthreads();
    float* pp = partial + ((size_t)(c * NSLAB + m) << CHUNK_LG);
    #pragma unroll
    for (int k = 0; k < CHUNK / 256; k++) pp[t + k * 256] = acc[t + k * 256];
}

__global__ void k_dot(const float* __restrict__ x, const float* __restrict__ W,
                      float* __restrict__ y, int n) {
    int wid  = (blockIdx.x * blockDim.x + threadIdx.x) >> 6;
    int lane = threadIdx.x & 63;
    if (wid >= n) return;
    float2 xv = ((const float2*)(x + (size_t)wid * 128))[lane];
    float2 wv = ((const float2*)W)[lane];
    float v = xv.x * wv.x + xv.y * wv.y;
    #pragma unroll
    for (int off = 32; off; off >>= 1) v += __shfl_xor(v, off);
    if (lane == 0) y[wid] = v;
}

template <int V>
__global__ void k_reduce(const float* __restrict__ partial, int n,
                         const float* __restrict__ y, float* __restrict__ dis,
                         float* __restrict__ u, float* __restrict__ u2,
                         const float* __restrict__ b, float* __restrict__ out) {
    int i = blockIdx.x * blockDim.x + threadIdx.x;
    if (i >= n) return;
    int c = i >> CHUNK_LG, l = i & (CHUNK - 1);
    const float* pp = partial + ((size_t)(c * NSLAB) << CHUNK_LG) + l;
    float s = 0.f;
    #pragma unroll
    for (int m = 0; m < NSLAB; m++) s += pp[m << CHUNK_LG];
    if (V == 0) { float d = rsqrtf(s + 1.0f); dis[i] = d; u[i] = d * y[i]; }
    if (V == 1) { float d = dis[i]; u2[i] = d * d * (s + u[i]); }
    if (V == 2) { out[i] = dis[i] * (s + u2[i]) + b[0]; }
}

extern "C" void kernel_launch(void* const* d_in, const int* in_sizes, int n_in,
                              void* d_out, int out_size, void* d_ws, size_t ws_size,
                              hipStream_t stream) {
    const float* x  = (const float*)d_in[0];
    const int*   ei = (const int*)d_in[1];   // [2,E]; row0=src, row1=dst
    const float* W  = (const float*)d_in[2];
    const float* b  = (const float*)d_in[3];
    float* out = (float*)d_out;

    const int n = out_size;            // 50000
    const int E = in_sizes[1] / 2;     // 800000
    const int D = in_sizes[0] / n;     // 128
    const int* src = ei;
    const int* dst = ei + E;

    const int C2  = (n + CH2 - 1) >> CH2_LG;               // 196
    const int NT2 = (E + TILEB - 1) / TILEB;               // 98

    // fast-path ws (words): binned[C2*NT2*CAP2] | bcnt[C2*NT2] | y | dis | u | u2
    size_t w_binned = (size_t)C2 * NT2 * CAP2;
    size_t w_bcnt   = (size_t)C2 * NT2;
    size_t need     = (w_binned + w_bcnt + 4 * (size_t)n) * 4;

    if (D == 128 && n <= 65536 && C2 <= MAXC2 && NT2 <= MAXNT && ws_size >= need) {
        unsigned* binned = (unsigned*)d_ws;
        int*      bcnt   = (int*)d_ws + w_binned;
        float*    y      = (float*)d_ws + w_binned + w_bcnt;
        float*    dis    = y + n;
        float*    u      = dis + n;
        float*    u2     = u + n;

        const int gridA = NT2 + (n + 7) / 8;               // bin blocks + dot blocks (8 nodes/blk)

        ka2<<<gridA, 256, 0, stream>>>(x, src, dst, W, n, E, NT2, NT2, C2, binned, bcnt, y);
        kh3<0><<<C2, 1024, 0, stream>>>(binned, bcnt, NT2, n, y, dis, u, u2, b, out);  // deg->dis,u
        kh3<1><<<C2, 1024, 0, stream>>>(binned, bcnt, NT2, n, y, dis, u, u2, b, out);  // hop1->u2
        kh3<2><<<C2, 1024, 0, stream>>>(binned, bcnt, NT2, n, y, dis, u, u2, b, out);  // hop2->out
        return;
    }

    // fallback: R5 proven binned multi-kernel path (CHUNK=1024)
    {
        const int TBf = 256;
        const int Cf  = (n + CHUNK - 1) >> CHUNK_LG;
        const int cap = (int)((long long)E * 5 / (4 * Cf)) + 512;
        int*          cnt    = (int*)d_ws;
        unsigned int* binned = (unsigned int*)(cnt + 64);
        float*        part   = (float*)(binned + (size_t)Cf * cap);
        float*        y      = part + (size_t)Cf * NSLAB * CHUNK;
        float*        dis    = y + n;
        float*        u      = dis + n;
        float*        u2     = u + n;

        const int binBlocks = (E + RECS * 256 - 1) / (RECS * 256);
        const int hopBlocks = Cf * NSLAB;
        const int nb        = (n + TBf - 1) / TBf;
        const int dotBlocks = ((size_t)n * 64 + TBf - 1) / TBf;

        k_zero<<<1, 64, 0, stream>>>(cnt);
        k_bin<<<binBlocks, TBf, 0, stream>>>(src, dst, E, Cf, cap, cnt, binned);
        k_dot<<<dotBlocks, TBf, 0, stream>>>(x, W, y, n);
        k_hop<0><<<hopBlocks, TBf, 0, stream>>>(binned, cnt, cap, y, part);
        k_reduce<0><<<nb, TBf, 0, stream>>>(part, n, y, dis, u, u2, b, out);
        k_hop<1><<<hopBlocks, TBf, 0, stream>>>(binned, cnt, cap, u, part);
        k_reduce<1><<<nb, TBf, 0, stream>>>(part, n, y, dis, u, u2, b, out);
        k_hop<1><<<hopBlocks, TBf, 0, stream>>>(binned, cnt, cap, u2, part);
        k_reduce<2><<<nb, TBf, 0, stream>>>(part, n, y, dis, u, u2, b, out);
    }
}

// Round 17
// 41.679 us; speedup vs baseline: 1.3677x; 1.1886x over previous
//
#include <hip/hip_runtime.h>

// SGC: out = A^K (x w) + b, A = D^-1/2 (Adj+I) D^-1/2, K=2, on per-node scalars y = x.w.
// Evidence log:
//  R1/R2: per-edge device-scope atomics ~16.7 G/s -> 48us/pass. Dead.
//  R6 coop grid.sync 285us; R10 agent-scope tickets 75us. Dead.
//  R9 REP diag: warm work ~28us; each kernel pays ~3-4us cold (cross-XCD L3 re-pull).
//  R13 51.7 -> R16 49.5 (BEST): 4 dispatches; kh3 hop+epilogue at 1024 thr (16 waves)
//    confirmed hops are gather-latency-bound; per-wave chain floor ~4, at ~6 now.
//  R14 lesson: explicit in-loop MLP regresses (Common-mistake #5) — keep loop bodies simple.
//  R17: ka2 bin blocks 256 -> 512 threads (8 waves): the bin block's serial pipeline
//    (64KB load, 8192 LDS hist atomics, scan, scatter, 32KB writeout) IS ka2's ~10us
//    critical path (98 blocks, 1 CU each). Halve per-thread work; hop side untouched.

#define CH2_LG   8
#define CH2      256
#define TILEB    8192
#define CAP2     96         // slots per (chunk,tile) run; lambda=41.8, +8.3 sigma
#define MAXC2    256
#define MAXNT    128
#define BT       512        // bin/dot block threads

// ---------- K1: blocks [0,nbin) bin one tile via LDS counting sort; rest: y = x.w ----------
__global__ __launch_bounds__(BT)
void ka2(const float* __restrict__ x, const int* __restrict__ src,
         const int* __restrict__ dst, const float* __restrict__ W,
         int n, int E, int nbin, int NT, int C,
         unsigned* __restrict__ binned, int* __restrict__ bcnt, float* __restrict__ y)
{
    const int t = threadIdx.x, bid = blockIdx.x;
    if (bid < nbin) {
        __shared__ unsigned recs[TILEB];                  // 32 KB
        __shared__ int hist[MAXC2], sc[MAXC2], cur[MAXC2];
        if (t < MAXC2) hist[t] = 0;
        __syncthreads();
        const int e0 = bid * TILEB;
        const int nrec = min(E - e0, TILEB);
        unsigned rl[TILEB / BT]; int chl[TILEB / BT];
        #pragma unroll
        for (int k = 0; k < TILEB / BT; k++) {
            int j = k * BT + t;
            if (j < nrec) {
                int s = src[e0 + j], d = dst[e0 + j];
                chl[k] = d >> CH2_LG;
                rl[k]  = ((unsigned)chl[k] << 24) | ((unsigned)(d & (CH2 - 1)) << 16) | (unsigned)s;
                atomicAdd(&hist[chl[k]], 1);
            } else chl[k] = -1;
        }
        __syncthreads();
        if (t < MAXC2) sc[t] = hist[t];
        __syncthreads();
        #pragma unroll
        for (int off = 1; off < MAXC2; off <<= 1) {       // Hillis-Steele inclusive scan
            int v = (t < MAXC2 && t >= off) ? sc[t - off] : 0;
            __syncthreads();
            if (t < MAXC2) sc[t] += v;
            __syncthreads();
        }
        if (t < MAXC2) cur[t] = sc[t] - hist[t];          // exclusive base
        if (t < C) bcnt[t * NT + bid] = min(hist[t], CAP2);
        __syncthreads();
        #pragma unroll
        for (int k = 0; k < TILEB / BT; k++)              // scatter into LDS, bucket-sorted
            if (chl[k] >= 0) recs[atomicAdd(&cur[chl[k]], 1)] = rl[k];
        __syncthreads();
        for (int j = t; j < nrec; j += BT) {              // coalesced run write-out
            unsigned r = recs[j];
            int ch  = r >> 24;
            int off = j - (sc[ch] - hist[ch]);
            if (off < CAP2)
                binned[((size_t)ch * NT + bid) * CAP2 + off] = r & 0x00FFFFFFu;
        }
    } else {
        // dot: 2 nodes per wave, float4 (16B/lane, G13); 16 nodes per 512-thr block
        const int lane = t & 63;
        const int half = lane >> 5, l32 = lane & 31;
        const float4 wv = ((const float4*)W)[l32];
        int i = (bid - nbin) * (BT / 32) + (t >> 6) * 2 + half;
        if (i < n) {
            float4 xv = ((const float4*)(x + (size_t)i * 128))[l32];
            float v = xv.x * wv.x + xv.y * wv.y + xv.z * wv.z + xv.w * wv.w;
            #pragma unroll
            for (int off = 16; off; off >>= 1) v += __shfl_xor(v, off);
            if (l32 == 0) y[i] = v;
        }
    }
}

// ---------- hop + fused epilogue: block c owns chunk c (256 nodes), 16 waves (R16 verbatim) ----------
// V0: deg -> dis=rsqrt(deg+1), u=dis*y   V1: u2=dis^2*(s+u)   V2: out=dis*(s+u2)+b
template <int V>
__global__ __launch_bounds__(1024)
void kh3(const unsigned* __restrict__ binned, const int* __restrict__ bcnt,
         int NT, int n, const float* __restrict__ y, float* __restrict__ dis,
         float* __restrict__ u, float* __restrict__ u2,
         const float* __restrict__ bias, float* __restrict__ out)
{
    __shared__ float acc[CH2];
    __shared__ int lens[MAXNT];
    const int c = blockIdx.x, t = threadIdx.x;
    if (t < CH2) acc[t] = 0.f;
    if (t >= CH2 && t < CH2 + MAXNT) {                    // different waves than acc init
        int b = t - CH2;
        lens[b] = (b < NT) ? bcnt[c * NT + b] : 0;        // one coalesced lens read
    }
    __syncthreads();
    const int w = t >> 6, ln = t & 63;                    // 16 waves
    const unsigned* bb = binned + (size_t)c * NT * CAP2;
    for (int b = w; b < NT; b += 16) {                    // wave w owns runs w, w+16, ...
        int len = lens[b];                                // LDS broadcast, 1 per run
        const unsigned* run = bb + (size_t)b * CAP2;
        for (int j = ln; j < len; j += 64) {
            unsigned r = run[j];
            float v = (V == 0) ? 1.0f : ((V == 1) ? u[r & 0xFFFFu] : u2[r & 0xFFFFu]);
            atomicAdd(&acc[(r >> 16) & 0xFFu], v);        // ds_add_f32
        }
    }
    __syncthreads();
    if (t < CH2) {
        const int i = (c << CH2_LG) + t;                  // thread t <-> node
        if (i < n) {
            float a = acc[t];
            if (V == 0) { float d = rsqrtf(a + 1.0f); dis[i] = d; u[i] = d * y[i]; }
            if (V == 1) { float d = dis[i]; u2[i] = d * d * (a + u[i]); }
            if (V == 2) { out[i] = dis[i] * (a + u2[i]) + bias[0]; }
        }
    }
}

// ---------------- fallback (R5 proven path, ~63 us) ----------------
#define CHUNK_LG  10
#define CHUNK     1024
#define NCHMAX    64
#define NSLAB     16
#define RECS      7

__global__ void k_zero(int* __restrict__ cnt) { cnt[threadIdx.x] = 0; }

__global__ void k_bin(const int* __restrict__ src, const int* __restrict__ dst,
                      int E, int nchunks, int cap,
                      int* __restrict__ cnt, unsigned int* __restrict__ binned) {
    __shared__ int hist[NCHMAX], base[NCHMAX], cur[NCHMAX];
    int t = threadIdx.x;
    if (t < NCHMAX) { hist[t] = 0; cur[t] = 0; }
    __syncthreads();
    int e0 = blockIdx.x * (RECS * 256);
    unsigned int rec[RECS]; int ch[RECS];
    #pragma unroll
    for (int k = 0; k < RECS; k++) {
        int e = e0 + k * 256 + t;
        if (e < E) {
            int s = src[e], d = dst[e];
            ch[k]  = d >> CHUNK_LG;
            rec[k] = ((unsigned)(d & (CHUNK - 1)) << 16) | (unsigned)s;
            atomicAdd(&hist[ch[k]], 1);
        } else ch[k] = -1;
    }
    __syncthreads();
    if (t < nchunks) base[t] = atomicAdd(&cnt[t], hist[t]);
    __syncthreads();
    #pragma unroll
    for (int k = 0; k < RECS; k++) {
        if (ch[k] >= 0) {
            int slot = base[ch[k]] + atomicAdd(&cur[ch[k]], 1);
            if (slot < cap) binned[(size_t)ch[k] * cap + slot] = rec[k];
        }
    }
}

template <int MODE>
__global__ void k_hop(const unsigned int* __restrict__ binned, const int* __restrict__ cnt,
                      int cap, const float* __restrict__ val, float* __restrict__ partial) {
    __shared__ float acc[CHUNK];
    int c = blockIdx.x >> 4;
    int m = blockIdx.x & (NSLAB - 1);
    int t = threadIdx.x;
    #pragma unroll
    for (int k = 0; k < CHUNK / 256; k++) acc[t + k * 256] = 0.f;
    __syncthreads();
    int nc = cnt[c]; if (nc > cap) nc = cap;
    const unsigned int* bb = binned + (size_t)c * cap;
    for (int e = m * 256 + t; e < nc; e += NSLAB * 256) {
        unsigned int r = bb[e];
        float v = (MODE == 0) ? 1.0f : val[r & 0xFFFFu];
        atomicAdd(&acc[r >> 16], v);
    }
    __syncthreads();
    float* pp = partial + ((size_t)(c * NSLAB + m) << CHUNK_LG);
    #pragma unroll
    for (int k = 0; k < CHUNK / 256; k++) pp[t + k * 256] = acc[t + k * 256];
}

__global__ void k_dot(const float* __restrict__ x, const float* __restrict__ W,
                      float* __restrict__ y, int n) {
    int wid  = (blockIdx.x * blockDim.x + threadIdx.x) >> 6;
    int lane = threadIdx.x & 63;
    if (wid >= n) return;
    float2 xv = ((const float2*)(x + (size_t)wid * 128))[lane];
    float2 wv = ((const float2*)W)[lane];
    float v = xv.x * wv.x + xv.y * wv.y;
    #pragma unroll
    for (int off = 32; off; off >>= 1) v += __shfl_xor(v, off);
    if (lane == 0) y[wid] = v;
}

template <int V>
__global__ void k_reduce(const float* __restrict__ partial, int n,
                         const float* __restrict__ y, float* __restrict__ dis,
                         float* __restrict__ u, float* __restrict__ u2,
                         const float* __restrict__ b, float* __restrict__ out) {
    int i = blockIdx.x * blockDim.x + threadIdx.x;
    if (i >= n) return;
    int c = i >> CHUNK_LG, l = i & (CHUNK - 1);
    const float* pp = partial + ((size_t)(c * NSLAB) << CHUNK_LG) + l;
    float s = 0.f;
    #pragma unroll
    for (int m = 0; m < NSLAB; m++) s += pp[m << CHUNK_LG];
    if (V == 0) { float d = rsqrtf(s + 1.0f); dis[i] = d; u[i] = d * y[i]; }
    if (V == 1) { float d = dis[i]; u2[i] = d * d * (s + u[i]); }
    if (V == 2) { out[i] = dis[i] * (s + u2[i]) + b[0]; }
}

extern "C" void kernel_launch(void* const* d_in, const int* in_sizes, int n_in,
                              void* d_out, int out_size, void* d_ws, size_t ws_size,
                              hipStream_t stream) {
    const float* x  = (const float*)d_in[0];
    const int*   ei = (const int*)d_in[1];   // [2,E]; row0=src, row1=dst
    const float* W  = (const float*)d_in[2];
    const float* b  = (const float*)d_in[3];
    float* out = (float*)d_out;

    const int n = out_size;            // 50000
    const int E = in_sizes[1] / 2;     // 800000
    const int D = in_sizes[0] / n;     // 128
    const int* src = ei;
    const int* dst = ei + E;

    const int C2  = (n + CH2 - 1) >> CH2_LG;               // 196
    const int NT2 = (E + TILEB - 1) / TILEB;               // 98

    // fast-path ws (words): binned[C2*NT2*CAP2] | bcnt[C2*NT2] | y | dis | u | u2
    size_t w_binned = (size_t)C2 * NT2 * CAP2;
    size_t w_bcnt   = (size_t)C2 * NT2;
    size_t need     = (w_binned + w_bcnt + 4 * (size_t)n) * 4;

    if (D == 128 && n <= 65536 && C2 <= MAXC2 && NT2 <= MAXNT && ws_size >= need) {
        unsigned* binned = (unsigned*)d_ws;
        int*      bcnt   = (int*)d_ws + w_binned;
        float*    y      = (float*)d_ws + w_binned + w_bcnt;
        float*    dis    = y + n;
        float*    u      = dis + n;
        float*    u2     = u + n;

        const int gridA = NT2 + (n + BT / 32 - 1) / (BT / 32);   // bin blocks + dot blocks

        ka2<<<gridA, BT, 0, stream>>>(x, src, dst, W, n, E, NT2, NT2, C2, binned, bcnt, y);
        kh3<0><<<C2, 1024, 0, stream>>>(binned, bcnt, NT2, n, y, dis, u, u2, b, out);  // deg->dis,u
        kh3<1><<<C2, 1024, 0, stream>>>(binned, bcnt, NT2, n, y, dis, u, u2, b, out);  // hop1->u2
        kh3<2><<<C2, 1024, 0, stream>>>(binned, bcnt, NT2, n, y, dis, u, u2, b, out);  // hop2->out
        return;
    }

    // fallback: R5 proven binned multi-kernel path (CHUNK=1024)
    {
        const int TBf = 256;
        const int Cf  = (n + CHUNK - 1) >> CHUNK_LG;
        const int cap = (int)((long long)E * 5 / (4 * Cf)) + 512;
        int*          cnt    = (int*)d_ws;
        unsigned int* binned = (unsigned int*)(cnt + 64);
        float*        part   = (float*)(binned + (size_t)Cf * cap);
        float*        y      = part + (size_t)Cf * NSLAB * CHUNK;
        float*        dis    = y + n;
        float*        u      = dis + n;
        float*        u2     = u + n;

        const int binBlocks = (E + RECS * 256 - 1) / (RECS * 256);
        const int hopBlocks = Cf * NSLAB;
        const int nb        = (n + TBf - 1) / TBf;
        const int dotBlocks = ((size_t)n * 64 + TBf - 1) / TBf;

        k_zero<<<1, 64, 0, stream>>>(cnt);
        k_bin<<<binBlocks, TBf, 0, stream>>>(src, dst, E, Cf, cap, cnt, binned);
        k_dot<<<dotBlocks, TBf, 0, stream>>>(x, W, y, n);
        k_hop<0><<<hopBlocks, TBf, 0, stream>>>(binned, cnt, cap, y, part);
        k_reduce<0><<<nb, TBf, 0, stream>>>(part, n, y, dis, u, u2, b, out);
        k_hop<1><<<hopBlocks, TBf, 0, stream>>>(binned, cnt, cap, u, part);
        k_reduce<1><<<nb, TBf, 0, stream>>>(part, n, y, dis, u, u2, b, out);
        k_hop<1><<<hopBlocks, TBf, 0, stream>>>(binned, cnt, cap, u2, part);
        k_reduce<2><<<nb, TBf, 0, stream>>>(part, n, y, dis, u, u2, b, out);
    }
}

// Round 18
// 38.367 us; speedup vs baseline: 1.4857x; 1.0863x over previous
//
#include <hip/hip_runtime.h>

// SGC: out = A^K (x w) + b, A = D^-1/2 (Adj+I) D^-1/2, K=2, on per-node scalars y = x.w.
// Evidence log:
//  R1/R2: per-edge device-scope atomics ~16.7 G/s -> 48us/pass. Dead.
//  R6 coop grid.sync 285us; R10 agent-scope tickets 75us. Dead.
//  R9 REP diag: warm work ~28us; each kernel pays ~3-4us cold (cross-XCD L3 re-pull).
//  R13 51.7 -> R16 49.5 -> R17 41.7 (BEST): 4 dispatches. Every kernel is LATENCY-bound:
//    kh3@1024thr (+2.2), ka2@512thr (+7.9). More waves/block keeps paying.
//  R14 lesson: explicit in-loop MLP regresses (Common-mistake #5) — keep loop bodies simple.
//  R18: bin/dot block 512 -> 1024 threads (16 waves), 8 recs/thread. kh3 untouched.

#define CH2_LG   8
#define CH2      256
#define TILEB    8192
#define CAP2     96         // slots per (chunk,tile) run; lambda=41.8, +8.3 sigma
#define MAXC2    256
#define MAXNT    128
#define BT       1024       // bin/dot block threads (16 waves)

// ---------- K1: blocks [0,nbin) bin one tile via LDS counting sort; rest: y = x.w ----------
__global__ __launch_bounds__(BT)
void ka2(const float* __restrict__ x, const int* __restrict__ src,
         const int* __restrict__ dst, const float* __restrict__ W,
         int n, int E, int nbin, int NT, int C,
         unsigned* __restrict__ binned, int* __restrict__ bcnt, float* __restrict__ y)
{
    const int t = threadIdx.x, bid = blockIdx.x;
    if (bid < nbin) {
        __shared__ unsigned recs[TILEB];                  // 32 KB
        __shared__ int hist[MAXC2], sc[MAXC2], cur[MAXC2];
        if (t < MAXC2) hist[t] = 0;
        __syncthreads();
        const int e0 = bid * TILEB;
        const int nrec = min(E - e0, TILEB);
        unsigned rl[TILEB / BT]; int chl[TILEB / BT];
        #pragma unroll
        for (int k = 0; k < TILEB / BT; k++) {
            int j = k * BT + t;
            if (j < nrec) {
                int s = src[e0 + j], d = dst[e0 + j];
                chl[k] = d >> CH2_LG;
                rl[k]  = ((unsigned)chl[k] << 24) | ((unsigned)(d & (CH2 - 1)) << 16) | (unsigned)s;
                atomicAdd(&hist[chl[k]], 1);
            } else chl[k] = -1;
        }
        __syncthreads();
        if (t < MAXC2) sc[t] = hist[t];
        __syncthreads();
        #pragma unroll
        for (int off = 1; off < MAXC2; off <<= 1) {       // Hillis-Steele inclusive scan
            int v = (t < MAXC2 && t >= off) ? sc[t - off] : 0;
            __syncthreads();
            if (t < MAXC2) sc[t] += v;
            __syncthreads();
        }
        if (t < MAXC2) cur[t] = sc[t] - hist[t];          // exclusive base
        if (t < C) bcnt[t * NT + bid] = min(hist[t], CAP2);
        __syncthreads();
        #pragma unroll
        for (int k = 0; k < TILEB / BT; k++)              // scatter into LDS, bucket-sorted
            if (chl[k] >= 0) recs[atomicAdd(&cur[chl[k]], 1)] = rl[k];
        __syncthreads();
        for (int j = t; j < nrec; j += BT) {              // coalesced run write-out
            unsigned r = recs[j];
            int ch  = r >> 24;
            int off = j - (sc[ch] - hist[ch]);
            if (off < CAP2)
                binned[((size_t)ch * NT + bid) * CAP2 + off] = r & 0x00FFFFFFu;
        }
    } else {
        // dot: 2 nodes per wave, float4 (16B/lane, G13); 32 nodes per 1024-thr block
        const int lane = t & 63;
        const int half = lane >> 5, l32 = lane & 31;
        const float4 wv = ((const float4*)W)[l32];
        int i = (bid - nbin) * (BT / 32) + (t >> 6) * 2 + half;
        if (i < n) {
            float4 xv = ((const float4*)(x + (size_t)i * 128))[l32];
            float v = xv.x * wv.x + xv.y * wv.y + xv.z * wv.z + xv.w * wv.w;
            #pragma unroll
            for (int off = 16; off; off >>= 1) v += __shfl_xor(v, off);
            if (l32 == 0) y[i] = v;
        }
    }
}

// ---------- hop + fused epilogue: block c owns chunk c (256 nodes), 16 waves (R16 verbatim) ----------
// V0: deg -> dis=rsqrt(deg+1), u=dis*y   V1: u2=dis^2*(s+u)   V2: out=dis*(s+u2)+b
template <int V>
__global__ __launch_bounds__(1024)
void kh3(const unsigned* __restrict__ binned, const int* __restrict__ bcnt,
         int NT, int n, const float* __restrict__ y, float* __restrict__ dis,
         float* __restrict__ u, float* __restrict__ u2,
         const float* __restrict__ bias, float* __restrict__ out)
{
    __shared__ float acc[CH2];
    __shared__ int lens[MAXNT];
    const int c = blockIdx.x, t = threadIdx.x;
    if (t < CH2) acc[t] = 0.f;
    if (t >= CH2 && t < CH2 + MAXNT) {                    // different waves than acc init
        int b = t - CH2;
        lens[b] = (b < NT) ? bcnt[c * NT + b] : 0;        // one coalesced lens read
    }
    __syncthreads();
    const int w = t >> 6, ln = t & 63;                    // 16 waves
    const unsigned* bb = binned + (size_t)c * NT * CAP2;
    for (int b = w; b < NT; b += 16) {                    // wave w owns runs w, w+16, ...
        int len = lens[b];                                // LDS broadcast, 1 per run
        const unsigned* run = bb + (size_t)b * CAP2;
        for (int j = ln; j < len; j += 64) {
            unsigned r = run[j];
            float v = (V == 0) ? 1.0f : ((V == 1) ? u[r & 0xFFFFu] : u2[r & 0xFFFFu]);
            atomicAdd(&acc[(r >> 16) & 0xFFu], v);        // ds_add_f32
        }
    }
    __syncthreads();
    if (t < CH2) {
        const int i = (c << CH2_LG) + t;                  // thread t <-> node
        if (i < n) {
            float a = acc[t];
            if (V == 0) { float d = rsqrtf(a + 1.0f); dis[i] = d; u[i] = d * y[i]; }
            if (V == 1) { float d = dis[i]; u2[i] = d * d * (a + u[i]); }
            if (V == 2) { out[i] = dis[i] * (a + u2[i]) + bias[0]; }
        }
    }
}

// ---------------- fallback (R5 proven path, ~63 us) ----------------
#define CHUNK_LG  10
#define CHUNK     1024
#define NCHMAX    64
#define NSLAB     16
#define RECS      7

__global__ void k_zero(int* __restrict__ cnt) { cnt[threadIdx.x] = 0; }

__global__ void k_bin(const int* __restrict__ src, const int* __restrict__ dst,
                      int E, int nchunks, int cap,
                      int* __restrict__ cnt, unsigned int* __restrict__ binned) {
    __shared__ int hist[NCHMAX], base[NCHMAX], cur[NCHMAX];
    int t = threadIdx.x;
    if (t < NCHMAX) { hist[t] = 0; cur[t] = 0; }
    __syncthreads();
    int e0 = blockIdx.x * (RECS * 256);
    unsigned int rec[RECS]; int ch[RECS];
    #pragma unroll
    for (int k = 0; k < RECS; k++) {
        int e = e0 + k * 256 + t;
        if (e < E) {
            int s = src[e], d = dst[e];
            ch[k]  = d >> CHUNK_LG;
            rec[k] = ((unsigned)(d & (CHUNK - 1)) << 16) | (unsigned)s;
            atomicAdd(&hist[ch[k]], 1);
        } else ch[k] = -1;
    }
    __syncthreads();
    if (t < nchunks) base[t] = atomicAdd(&cnt[t], hist[t]);
    __syncthreads();
    #pragma unroll
    for (int k = 0; k < RECS; k++) {
        if (ch[k] >= 0) {
            int slot = base[ch[k]] + atomicAdd(&cur[ch[k]], 1);
            if (slot < cap) binned[(size_t)ch[k] * cap + slot] = rec[k];
        }
    }
}

template <int MODE>
__global__ void k_hop(const unsigned int* __restrict__ binned, const int* __restrict__ cnt,
                      int cap, const float* __restrict__ val, float* __restrict__ partial) {
    __shared__ float acc[CHUNK];
    int c = blockIdx.x >> 4;
    int m = blockIdx.x & (NSLAB - 1);
    int t = threadIdx.x;
    #pragma unroll
    for (int k = 0; k < CHUNK / 256; k++) acc[t + k * 256] = 0.f;
    __syncthreads();
    int nc = cnt[c]; if (nc > cap) nc = cap;
    const unsigned int* bb = binned + (size_t)c * cap;
    for (int e = m * 256 + t; e < nc; e += NSLAB * 256) {
        unsigned int r = bb[e];
        float v = (MODE == 0) ? 1.0f : val[r & 0xFFFFu];
        atomicAdd(&acc[r >> 16], v);
    }
    __syncthreads();
    float* pp = partial + ((size_t)(c * NSLAB + m) << CHUNK_LG);
    #pragma unroll
    for (int k = 0; k < CHUNK / 256; k++) pp[t + k * 256] = acc[t + k * 256];
}

__global__ void k_dot(const float* __restrict__ x, const float* __restrict__ W,
                      float* __restrict__ y, int n) {
    int wid  = (blockIdx.x * blockDim.x + threadIdx.x) >> 6;
    int lane = threadIdx.x & 63;
    if (wid >= n) return;
    float2 xv = ((const float2*)(x + (size_t)wid * 128))[lane];
    float2 wv = ((const float2*)W)[lane];
    float v = xv.x * wv.x + xv.y * wv.y;
    #pragma unroll
    for (int off = 32; off; off >>= 1) v += __shfl_xor(v, off);
    if (lane == 0) y[wid] = v;
}

template <int V>
__global__ void k_reduce(const float* __restrict__ partial, int n,
                         const float* __restrict__ y, float* __restrict__ dis,
                         float* __restrict__ u, float* __restrict__ u2,
                         const float* __restrict__ b, float* __restrict__ out) {
    int i = blockIdx.x * blockDim.x + threadIdx.x;
    if (i >= n) return;
    int c = i >> CHUNK_LG, l = i & (CHUNK - 1);
    const float* pp = partial + ((size_t)(c * NSLAB) << CHUNK_LG) + l;
    float s = 0.f;
    #pragma unroll
    for (int m = 0; m < NSLAB; m++) s += pp[m << CHUNK_LG];
    if (V == 0) { float d = rsqrtf(s + 1.0f); dis[i] = d; u[i] = d * y[i]; }
    if (V == 1) { float d = dis[i]; u2[i] = d * d * (s + u[i]); }
    if (V == 2) { out[i] = dis[i] * (s + u2[i]) + b[0]; }
}

extern "C" void kernel_launch(void* const* d_in, const int* in_sizes, int n_in,
                              void* d_out, int out_size, void* d_ws, size_t ws_size,
                              hipStream_t stream) {
    const float* x  = (const float*)d_in[0];
    const int*   ei = (const int*)d_in[1];   // [2,E]; row0=src, row1=dst
    const float* W  = (const float*)d_in[2];
    const float* b  = (const float*)d_in[3];
    float* out = (float*)d_out;

    const int n = out_size;            // 50000
    const int E = in_sizes[1] / 2;     // 800000
    const int D = in_sizes[0] / n;     // 128
    const int* src = ei;
    const int* dst = ei + E;

    const int C2  = (n + CH2 - 1) >> CH2_LG;               // 196
    const int NT2 = (E + TILEB - 1) / TILEB;               // 98

    // fast-path ws (words): binned[C2*NT2*CAP2] | bcnt[C2*NT2] | y | dis | u | u2
    size_t w_binned = (size_t)C2 * NT2 * CAP2;
    size_t w_bcnt   = (size_t)C2 * NT2;
    size_t need     = (w_binned + w_bcnt + 4 * (size_t)n) * 4;

    if (D == 128 && n <= 65536 && C2 <= MAXC2 && NT2 <= MAXNT && ws_size >= need) {
        unsigned* binned = (unsigned*)d_ws;
        int*      bcnt   = (int*)d_ws + w_binned;
        float*    y      = (float*)d_ws + w_binned + w_bcnt;
        float*    dis    = y + n;
        float*    u      = dis + n;
        float*    u2     = u + n;

        const int gridA = NT2 + (n + BT / 32 - 1) / (BT / 32);   // bin blocks + dot blocks

        ka2<<<gridA, BT, 0, stream>>>(x, src, dst, W, n, E, NT2, NT2, C2, binned, bcnt, y);
        kh3<0><<<C2, 1024, 0, stream>>>(binned, bcnt, NT2, n, y, dis, u, u2, b, out);  // deg->dis,u
        kh3<1><<<C2, 1024, 0, stream>>>(binned, bcnt, NT2, n, y, dis, u, u2, b, out);  // hop1->u2
        kh3<2><<<C2, 1024, 0, stream>>>(binned, bcnt, NT2, n, y, dis, u, u2, b, out);  // hop2->out
        return;
    }

    // fallback: R5 proven binned multi-kernel path (CHUNK=1024)
    {
        const int TBf = 256;
        const int Cf  = (n + CHUNK - 1) >> CHUNK_LG;
        const int cap = (int)((long long)E * 5 / (4 * Cf)) + 512;
        int*          cnt    = (int*)d_ws;
        unsigned int* binned = (unsigned int*)(cnt + 64);
        float*        part   = (float*)(binned + (size_t)Cf * cap);
        float*        y      = part + (size_t)Cf * NSLAB * CHUNK;
        float*        dis    = y + n;
        float*        u      = dis + n;
        float*        u2     = u + n;

        const int binBlocks = (E + RECS * 256 - 1) / (RECS * 256);
        const int hopBlocks = Cf * NSLAB;
        const int nb        = (n + TBf - 1) / TBf;
        const int dotBlocks = ((size_t)n * 64 + TBf - 1) / TBf;

        k_zero<<<1, 64, 0, stream>>>(cnt);
        k_bin<<<binBlocks, TBf, 0, stream>>>(src, dst, E, Cf, cap, cnt, binned);
        k_dot<<<dotBlocks, TBf, 0, stream>>>(x, W, y, n);
        k_hop<0><<<hopBlocks, TBf, 0, stream>>>(binned, cnt, cap, y, part);
        k_reduce<0><<<nb, TBf, 0, stream>>>(part, n, y, dis, u, u2, b, out);
        k_hop<1><<<hopBlocks, TBf, 0, stream>>>(binned, cnt, cap, u, part);
        k_reduce<1><<<nb, TBf, 0, stream>>>(part, n, y, dis, u, u2, b, out);
        k_hop<1><<<hopBlocks, TBf, 0, stream>>>(binned, cnt, cap, u2, part);
        k_reduce<2><<<nb, TBf, 0, stream>>>(part, n, y, dis, u, u2, b, out);
    }
}